// Round 10
// baseline (55.532 us; speedup 1.0000x reference)
//
#include <hip/hip_runtime.h>

typedef float f32x4 __attribute__((ext_vector_type(4)));

#define EPS 1e-8f

constexpr int D = 384;
constexpr int Q_PER_I = (D * D) / 4;        // 36864 float4 per i-slab
constexpr int P = 8;                        // parts per i
constexpr int Q_PER_PART = Q_PER_I / P;     // 4608 float4 per block slab (72 KB)
constexpr int THREADS_A = 256;
constexpr int ITERS_A = Q_PER_PART / THREADS_A; // 18 = 3 groups of 6
constexpr int J_PER_PART = D / P;           // 48 j-rows per part

__device__ __forceinline__ f32x4 ldnt(const f32x4* p) {
  return __builtin_nontemporal_load(p);
}
__device__ __forceinline__ float dot4(f32x4 a, f32x4 b) {
  return a.x * b.x + a.y * b.y + a.z * b.z + a.w * b.w;
}

// Kernel A: partials[b] = sum over a[i, jbase:jbase+48, :] * y[j] * z[k]
// 3072 blocks, 6 NT loads in flight per lane (a is read-once, 226 MB:
// stream it past the caches so it can't evict x from the 256 MB L3).
__global__ __launch_bounds__(THREADS_A, 8) void ctx_partial_kernel(
    const float* __restrict__ a,
    const float* __restrict__ y,
    const float* __restrict__ z,
    float* __restrict__ partials) {
  const int b = blockIdx.x;
  const int i = b >> 3;
  const int part = b & 7;
  const f32x4* a4 = reinterpret_cast<const f32x4*>(a) +
                    (size_t)i * Q_PER_I + (size_t)part * Q_PER_PART;
  const f32x4* z4 = reinterpret_cast<const f32x4*>(z);
  const int tid = threadIdx.x;
  const float* yb = y + part * J_PER_PART;

  // q = tid + it*256; k4 = q mod 96 has period 3; jl advances 16 per group of 6.
  int jl = tid / 96;                        // 0..2
  const int k4 = tid - jl * 96;             // 0..95
  int k4b = k4 + 64; if (k4b >= 96) k4b -= 96;
  int k4c = k4b + 64; if (k4c >= 96) k4c -= 96;
  const f32x4 zva = z4[k4];
  const f32x4 zvb = z4[k4b];
  const f32x4 zvc = z4[k4c];
  const int incA = (k4 >= 32) ? 3 : 2;
  const int incAB = incA + ((k4b >= 32) ? 3 : 2);

  const f32x4* ap = a4 + tid;
  float acc = 0.0f;
#pragma unroll
  for (int g = 0; g < ITERS_A / 6; ++g) {   // 3 groups of 6
    f32x4 av0 = ldnt(ap + 0 * THREADS_A);
    f32x4 av1 = ldnt(ap + 1 * THREADS_A);
    f32x4 av2 = ldnt(ap + 2 * THREADS_A);
    f32x4 av3 = ldnt(ap + 3 * THREADS_A);
    f32x4 av4 = ldnt(ap + 4 * THREADS_A);
    f32x4 av5 = ldnt(ap + 5 * THREADS_A);
    float y0 = yb[jl];
    float y1 = yb[jl + incA];
    float y2 = yb[jl + incAB];
    float y3 = yb[jl + 8];
    float y4 = yb[jl + 8 + incA];
    float y5 = yb[jl + 8 + incAB];
    acc += y0 * dot4(av0, zva);
    acc += y1 * dot4(av1, zvb);
    acc += y2 * dot4(av2, zvc);
    acc += y3 * dot4(av3, zva);
    acc += y4 * dot4(av4, zvb);
    acc += y5 * dot4(av5, zvc);
    ap += 6 * THREADS_A;
    jl += 16;
  }

  for (int off = 32; off > 0; off >>= 1)
    acc += __shfl_down(acc, off);

  __shared__ float sm[THREADS_A / 64];
  const int lane = tid & 63;
  const int w = tid >> 6;
  if (lane == 0) sm[w] = acc;
  __syncthreads();
  if (tid == 0) {
    float s = 0.0f;
#pragma unroll
    for (int k = 0; k < THREADS_A / 64; ++k) s += sm[k];
    partials[b] = s;
  }
}

// Kernel C: fold partials -> ctx in LDS, then matvec. Each wave owns 8
// ADJACENT rows; a row-pair is 192 float4 = exactly 3 full-width loads/lane.
// x loads are CACHED (x = 100.7 MB fits the 256 MB L3; retention across
// graph replays was measured at ~160 MB L3 hits in the fused variants).
__global__ __launch_bounds__(256, 8) void score_kernel(
    const float* __restrict__ x,
    const float* __restrict__ partials,
    float* __restrict__ out,
    int N) {
  __shared__ float ctx_s[D];
  const int tid = threadIdx.x;

  const f32x4* p4 = reinterpret_cast<const f32x4*>(partials);
  for (int t = tid; t < D; t += 256) {
    f32x4 v0 = p4[t * 2 + 0];
    f32x4 v1 = p4[t * 2 + 1];
    ctx_s[t] = (v0.x + v0.y + v0.z + v0.w) + (v1.x + v1.y + v1.z + v1.w);
  }
  __syncthreads();

  const float scale = 1.0f / (ctx_s[0] + EPS);
  const int lane = tid & 63;
  const int w = tid >> 6;
  const f32x4* c4 = reinterpret_cast<const f32x4*>(ctx_s);
  const f32x4 cvA = c4[lane];
  const f32x4 cvB = c4[(lane < 32) ? (lane + 64) : (lane - 32)];
  const f32x4 cvC = c4[lane + 32];
  const bool lo = (lane < 32);

  const f32x4* x4 = reinterpret_cast<const f32x4*>(x);
  const int waveId = blockIdx.x * 4 + w;    // 0..8191
  const int base = waveId * 8;              // 8 adjacent rows per wave

#pragma unroll
  for (int it = 0; it < 2; ++it) {
    const int r0 = base + it * 4;           // pairs (r0,r0+1), (r0+2,r0+3)
    const f32x4* q0 = x4 + (size_t)r0 * 96;
    const f32x4* q1 = q0 + 192;
    f32x4 a0 = q0[lane];
    f32x4 b0 = q0[64 + lane];
    f32x4 c0 = q0[128 + lane];
    f32x4 a1 = q1[lane];
    f32x4 b1 = q1[64 + lane];
    f32x4 c1 = q1[128 + lane];

    float t0 = dot4(b0, cvB);
    float t1 = dot4(b1, cvB);
    float sA0 = dot4(a0, cvA) + (lo ? t0 : 0.0f);
    float sB0 = dot4(c0, cvC) + (lo ? 0.0f : t0);
    float sA1 = dot4(a1, cvA) + (lo ? t1 : 0.0f);
    float sB1 = dot4(c1, cvC) + (lo ? 0.0f : t1);

#pragma unroll
    for (int off = 32; off > 0; off >>= 1) {
      sA0 += __shfl_down(sA0, off);
      sB0 += __shfl_down(sB0, off);
      sA1 += __shfl_down(sA1, off);
      sB1 += __shfl_down(sB1, off);
    }
    if (lane == 0) {
      out[r0 + 0] = sA0 * scale;
      out[r0 + 1] = sB0 * scale;
      out[r0 + 2] = sA1 * scale;
      out[r0 + 3] = sB1 * scale;
    }
  }
}

extern "C" void kernel_launch(void* const* d_in, const int* in_sizes, int n_in,
                              void* d_out, int out_size, void* d_ws, size_t ws_size,
                              hipStream_t stream) {
  const float* x = (const float*)d_in[0];  // [N, 384]
  const float* y = (const float*)d_in[1];  // [384]
  const float* z = (const float*)d_in[2];  // [384]
  const float* a = (const float*)d_in[3];  // [384, 384, 384]
  float* out = (float*)d_out;              // [N]

  const int N = in_sizes[0] / D;           // 65536
  float* partials = (float*)d_ws;          // D*P floats

  ctx_partial_kernel<<<D * P, THREADS_A, 0, stream>>>(a, y, z, partials);
  score_kernel<<<2048, 256, 0, stream>>>(x, partials, out, N);
}

// Round 11
// 55.272 us; speedup vs baseline: 1.0047x; 1.0047x over previous
//
#include <hip/hip_runtime.h>

typedef float f32x4 __attribute__((ext_vector_type(4)));

#define EPS 1e-8f

constexpr int D = 384;
constexpr int Q_PER_I = (D * D) / 4;          // 36864 float4 per i-slab
constexpr int P = 16;                         // parts per i
constexpr int UNITS = D * P;                  // 6144 units
constexpr int Q_PER_UNIT = Q_PER_I / P;       // 2304 float4 per unit (36 KB)
constexpr int THREADS_A = 256;
constexpr int ITERS_U = Q_PER_UNIT / THREADS_A; // 9 = 3 groups of 3
constexpr int J_PER_UNIT = D / P;             // 24 j-rows per unit
constexpr int GRID_A = 2048;                  // 8 blocks/CU, ONE scheduling round
constexpr int UNITS_PER_BLOCK = UNITS / GRID_A; // 3 contiguous units per block

__device__ __forceinline__ f32x4 ldnt(const f32x4* p) {
  return __builtin_nontemporal_load(p);
}
__device__ __forceinline__ float dot4(f32x4 a, f32x4 b) {
  return a.x * b.x + a.y * b.y + a.z * b.z + a.w * b.w;
}

// Kernel A: partials[unit] = sum over a[i, part*24:(part+1)*24, :] * y * z
// 2048 blocks exactly co-resident (no scheduling tail), each reads a
// contiguous 108 KB slab (3 units) with NT loads (read-once stream).
__global__ __launch_bounds__(THREADS_A, 8) void ctx_partial_kernel(
    const float* __restrict__ a,
    const float* __restrict__ y,
    const float* __restrict__ z,
    float* __restrict__ partials) {
  const int b = blockIdx.x;
  const int tid = threadIdx.x;
  const int lane = tid & 63;
  const int w = tid >> 6;
  const f32x4* z4 = reinterpret_cast<const f32x4*>(z);

  // q = tid + it*256; k4 = q mod 96 has period 3; jl advances 8 per 3 iters.
  int jl0 = tid / 96;                       // 0..2
  const int k4 = tid - jl0 * 96;            // 0..95
  int k4b = k4 + 64; if (k4b >= 96) k4b -= 96;
  int k4c = k4b + 64; if (k4c >= 96) k4c -= 96;
  const f32x4 zva = z4[k4];
  const f32x4 zvb = z4[k4b];
  const f32x4 zvc = z4[k4c];
  const int incA = (k4 >= 32) ? 3 : 2;
  const int incAB = incA + ((k4b >= 32) ? 3 : 2);

  __shared__ float sm[THREADS_A / 64];

#pragma unroll
  for (int ui = 0; ui < UNITS_PER_BLOCK; ++ui) {
    const int unit = b * UNITS_PER_BLOCK + ui;   // contiguous in memory
    const int i = unit >> 4;                     // unit / 16
    const int part = unit & 15;                  // unit % 16
    const f32x4* ap = reinterpret_cast<const f32x4*>(a) +
                      (size_t)unit * Q_PER_UNIT + tid;
    const float* yb = y + i * 0 + part * J_PER_UNIT;  // y rows for this part

    float acc = 0.0f;
    int jl = jl0;
#pragma unroll
    for (int g = 0; g < ITERS_U / 3; ++g) {      // 3 groups of 3
      f32x4 av0 = ldnt(ap + 0 * THREADS_A);
      f32x4 av1 = ldnt(ap + 1 * THREADS_A);
      f32x4 av2 = ldnt(ap + 2 * THREADS_A);
      float y0 = yb[jl];
      float y1 = yb[jl + incA];
      float y2 = yb[jl + incAB];
      acc += y0 * dot4(av0, zva);
      acc += y1 * dot4(av1, zvb);
      acc += y2 * dot4(av2, zvc);
      ap += 3 * THREADS_A;
      jl += 8;
    }

    for (int off = 32; off > 0; off >>= 1)
      acc += __shfl_down(acc, off);
    if (lane == 0) sm[w] = acc;
    __syncthreads();
    if (tid == 0) {
      float s = 0.0f;
#pragma unroll
      for (int k = 0; k < THREADS_A / 64; ++k) s += sm[k];
      partials[unit] = s;
    }
    __syncthreads();
  }
}

// Kernel C: fold partials (16/i) -> ctx in LDS, then matvec. Each wave owns 8
// ADJACENT rows; a row-pair is 192 float4 = exactly 3 full-width NT loads/lane.
__global__ __launch_bounds__(256, 8) void score_kernel(
    const float* __restrict__ x,
    const float* __restrict__ partials,
    float* __restrict__ out,
    int N) {
  __shared__ float ctx_s[D];
  const int tid = threadIdx.x;

  const f32x4* p4 = reinterpret_cast<const f32x4*>(partials);
  for (int t = tid; t < D; t += 256) {
    f32x4 v0 = p4[t * 4 + 0];
    f32x4 v1 = p4[t * 4 + 1];
    f32x4 v2 = p4[t * 4 + 2];
    f32x4 v3 = p4[t * 4 + 3];
    ctx_s[t] = ((v0.x + v0.y + v0.z + v0.w) + (v1.x + v1.y + v1.z + v1.w)) +
               ((v2.x + v2.y + v2.z + v2.w) + (v3.x + v3.y + v3.z + v3.w));
  }
  __syncthreads();

  const float scale = 1.0f / (ctx_s[0] + EPS);
  const int lane = tid & 63;
  const int w = tid >> 6;
  const f32x4* c4 = reinterpret_cast<const f32x4*>(ctx_s);
  const f32x4 cvA = c4[lane];
  const f32x4 cvB = c4[(lane < 32) ? (lane + 64) : (lane - 32)];
  const f32x4 cvC = c4[lane + 32];
  const bool lo = (lane < 32);

  const f32x4* x4 = reinterpret_cast<const f32x4*>(x);
  const int waveId = blockIdx.x * 4 + w;    // 0..8191
  const int base = waveId * 8;              // 8 adjacent rows per wave

#pragma unroll
  for (int it = 0; it < 2; ++it) {
    const int r0 = base + it * 4;           // pairs (r0,r0+1), (r0+2,r0+3)
    const f32x4* q0 = x4 + (size_t)r0 * 96;
    const f32x4* q1 = q0 + 192;
    f32x4 a0 = ldnt(q0 + lane);
    f32x4 b0 = ldnt(q0 + 64 + lane);
    f32x4 c0 = ldnt(q0 + 128 + lane);
    f32x4 a1 = ldnt(q1 + lane);
    f32x4 b1 = ldnt(q1 + 64 + lane);
    f32x4 c1 = ldnt(q1 + 128 + lane);

    float t0 = dot4(b0, cvB);
    float t1 = dot4(b1, cvB);
    float sA0 = dot4(a0, cvA) + (lo ? t0 : 0.0f);
    float sB0 = dot4(c0, cvC) + (lo ? 0.0f : t0);
    float sA1 = dot4(a1, cvA) + (lo ? t1 : 0.0f);
    float sB1 = dot4(c1, cvC) + (lo ? 0.0f : t1);

#pragma unroll
    for (int off = 32; off > 0; off >>= 1) {
      sA0 += __shfl_down(sA0, off);
      sB0 += __shfl_down(sB0, off);
      sA1 += __shfl_down(sA1, off);
      sB1 += __shfl_down(sB1, off);
    }
    if (lane == 0) {
      out[r0 + 0] = sA0 * scale;
      out[r0 + 1] = sB0 * scale;
      out[r0 + 2] = sA1 * scale;
      out[r0 + 3] = sB1 * scale;
    }
  }
}

extern "C" void kernel_launch(void* const* d_in, const int* in_sizes, int n_in,
                              void* d_out, int out_size, void* d_ws, size_t ws_size,
                              hipStream_t stream) {
  const float* x = (const float*)d_in[0];  // [N, 384]
  const float* y = (const float*)d_in[1];  // [384]
  const float* z = (const float*)d_in[2];  // [384]
  const float* a = (const float*)d_in[3];  // [384, 384, 384]
  float* out = (float*)d_out;              // [N]

  const int N = in_sizes[0] / D;           // 65536
  float* partials = (float*)d_ws;          // UNITS floats

  ctx_partial_kernel<<<GRID_A, THREADS_A, 0, stream>>>(a, y, z, partials);
  score_kernel<<<2048, 256, 0, stream>>>(x, partials, out, N);
}

// Round 12
// 53.603 us; speedup vs baseline: 1.0360x; 1.0311x over previous
//
#include <hip/hip_runtime.h>

typedef float f32x4 __attribute__((ext_vector_type(4)));

#define EPS 1e-8f

constexpr int D = 384;
constexpr int Q_PER_I = (D * D) / 4;        // 36864 float4 per i-slab
constexpr int P = 8;                        // parts per i
constexpr int Q_PER_PART = Q_PER_I / P;     // 4608 float4 per block slab (72 KB)
constexpr int THREADS_A = 256;
constexpr int ITERS_A = Q_PER_PART / THREADS_A; // 18 = 3 groups of 6
constexpr int J_PER_PART = D / P;           // 48 j-rows per part

__device__ __forceinline__ f32x4 ldnt(const f32x4* p) {
  return __builtin_nontemporal_load(p);
}
__device__ __forceinline__ float dot4(f32x4 a, f32x4 b) {
  return a.x * b.x + a.y * b.y + a.z * b.z + a.w * b.w;
}

// Kernel A: partials[b] = sum over a[i, jbase:jbase+48, :] * y[j] * z[k]
// 3072 blocks, 6 NT loads in flight per lane, VGPR capped for 8 waves/EU.
// Measured ~6.1 TB/s = per-CU HBM load ceiling (10 B/cyc/CU).
__global__ __launch_bounds__(THREADS_A, 8) void ctx_partial_kernel(
    const float* __restrict__ a,
    const float* __restrict__ y,
    const float* __restrict__ z,
    float* __restrict__ partials) {
  const int b = blockIdx.x;
  const int i = b >> 3;
  const int part = b & 7;
  const f32x4* a4 = reinterpret_cast<const f32x4*>(a) +
                    (size_t)i * Q_PER_I + (size_t)part * Q_PER_PART;
  const f32x4* z4 = reinterpret_cast<const f32x4*>(z);
  const int tid = threadIdx.x;
  const float* yb = y + part * J_PER_PART;

  // q = tid + it*256; k4 = q mod 96 has period 3; jl advances 16 per group of 6.
  int jl = tid / 96;                        // 0..2
  const int k4 = tid - jl * 96;             // 0..95
  int k4b = k4 + 64; if (k4b >= 96) k4b -= 96;
  int k4c = k4b + 64; if (k4c >= 96) k4c -= 96;
  const f32x4 zva = z4[k4];
  const f32x4 zvb = z4[k4b];
  const f32x4 zvc = z4[k4c];
  const int incA = (k4 >= 32) ? 3 : 2;
  const int incAB = incA + ((k4b >= 32) ? 3 : 2);

  const f32x4* ap = a4 + tid;
  float acc = 0.0f;
#pragma unroll
  for (int g = 0; g < ITERS_A / 6; ++g) {   // 3 groups of 6
    f32x4 av0 = ldnt(ap + 0 * THREADS_A);
    f32x4 av1 = ldnt(ap + 1 * THREADS_A);
    f32x4 av2 = ldnt(ap + 2 * THREADS_A);
    f32x4 av3 = ldnt(ap + 3 * THREADS_A);
    f32x4 av4 = ldnt(ap + 4 * THREADS_A);
    f32x4 av5 = ldnt(ap + 5 * THREADS_A);
    float y0 = yb[jl];
    float y1 = yb[jl + incA];
    float y2 = yb[jl + incAB];
    float y3 = yb[jl + 8];
    float y4 = yb[jl + 8 + incA];
    float y5 = yb[jl + 8 + incAB];
    acc += y0 * dot4(av0, zva);
    acc += y1 * dot4(av1, zvb);
    acc += y2 * dot4(av2, zvc);
    acc += y3 * dot4(av3, zva);
    acc += y4 * dot4(av4, zvb);
    acc += y5 * dot4(av5, zvc);
    ap += 6 * THREADS_A;
    jl += 16;
  }

  for (int off = 32; off > 0; off >>= 1)
    acc += __shfl_down(acc, off);

  __shared__ float sm[THREADS_A / 64];
  const int lane = tid & 63;
  const int w = tid >> 6;
  if (lane == 0) sm[w] = acc;
  __syncthreads();
  if (tid == 0) {
    float s = 0.0f;
#pragma unroll
    for (int k = 0; k < THREADS_A / 64; ++k) s += sm[k];
    partials[b] = s;
  }
}

// Kernel C: fold partials -> ctx in LDS, then matvec. Each wave owns 8
// ADJACENT rows; a row-pair is 192 float4 = exactly 3 full-width NT loads/lane.
// 2 pairs (6 NT loads) in flight per iteration. No idle lanes on loads.
__global__ __launch_bounds__(256, 8) void score_kernel(
    const float* __restrict__ x,
    const float* __restrict__ partials,
    float* __restrict__ out,
    int N) {
  __shared__ float ctx_s[D];
  const int tid = threadIdx.x;

  const f32x4* p4 = reinterpret_cast<const f32x4*>(partials);
  for (int t = tid; t < D; t += 256) {
    f32x4 v0 = p4[t * 2 + 0];
    f32x4 v1 = p4[t * 2 + 1];
    ctx_s[t] = (v0.x + v0.y + v0.z + v0.w) + (v1.x + v1.y + v1.z + v1.w);
  }
  __syncthreads();

  const float scale = 1.0f / (ctx_s[0] + EPS);
  const int lane = tid & 63;
  const int w = tid >> 6;
  const f32x4* c4 = reinterpret_cast<const f32x4*>(ctx_s);
  const f32x4 cvA = c4[lane];
  const f32x4 cvB = c4[(lane < 32) ? (lane + 64) : (lane - 32)];
  const f32x4 cvC = c4[lane + 32];
  const bool lo = (lane < 32);

  const f32x4* x4 = reinterpret_cast<const f32x4*>(x);
  const int waveId = blockIdx.x * 4 + w;    // 0..8191
  const int base = waveId * 8;              // 8 adjacent rows per wave

#pragma unroll
  for (int it = 0; it < 2; ++it) {
    const int r0 = base + it * 4;           // pairs (r0,r0+1), (r0+2,r0+3)
    const f32x4* q0 = x4 + (size_t)r0 * 96;
    const f32x4* q1 = q0 + 192;
    f32x4 a0 = ldnt(q0 + lane);
    f32x4 b0 = ldnt(q0 + 64 + lane);
    f32x4 c0 = ldnt(q0 + 128 + lane);
    f32x4 a1 = ldnt(q1 + lane);
    f32x4 b1 = ldnt(q1 + 64 + lane);
    f32x4 c1 = ldnt(q1 + 128 + lane);

    float t0 = dot4(b0, cvB);
    float t1 = dot4(b1, cvB);
    float sA0 = dot4(a0, cvA) + (lo ? t0 : 0.0f);
    float sB0 = dot4(c0, cvC) + (lo ? 0.0f : t0);
    float sA1 = dot4(a1, cvA) + (lo ? t1 : 0.0f);
    float sB1 = dot4(c1, cvC) + (lo ? 0.0f : t1);

#pragma unroll
    for (int off = 32; off > 0; off >>= 1) {
      sA0 += __shfl_down(sA0, off);
      sB0 += __shfl_down(sB0, off);
      sA1 += __shfl_down(sA1, off);
      sB1 += __shfl_down(sB1, off);
    }
    if (lane == 0) {
      out[r0 + 0] = sA0 * scale;
      out[r0 + 1] = sB0 * scale;
      out[r0 + 2] = sA1 * scale;
      out[r0 + 3] = sB1 * scale;
    }
  }
}

extern "C" void kernel_launch(void* const* d_in, const int* in_sizes, int n_in,
                              void* d_out, int out_size, void* d_ws, size_t ws_size,
                              hipStream_t stream) {
  const float* x = (const float*)d_in[0];  // [N, 384]
  const float* y = (const float*)d_in[1];  // [384]
  const float* z = (const float*)d_in[2];  // [384]
  const float* a = (const float*)d_in[3];  // [384, 384, 384]
  float* out = (float*)d_out;              // [N]

  const int N = in_sizes[0] / D;           // 65536
  float* partials = (float*)d_ws;          // D*P floats

  ctx_partial_kernel<<<D * P, THREADS_A, 0, stream>>>(a, y, z, partials);
  score_kernel<<<2048, 256, 0, stream>>>(x, partials, out, N);
}